// Round 5
// baseline (183.968 us; speedup 1.0000x reference)
//
#include <hip/hip_runtime.h>
#include <hip/hip_bf16.h>
#include <math.h>

#define N_NODES 50000
#define N_EDGES 800000
#define C 64
#define EPS_F 1.000001f

// ---- round-19: pad region cursors to one per cache line ----
// Round-18 post-mortem: K1 occupancy 0.35 over 980 co-resident blocks =>
// pre role exits at ~11 us, the 196 scatter blocks straggle to ~57 us; the
// scatter's cost was invariant across 4 rounds of changing its loads and
// arithmetic. The constant: pass B's 196x782 = 153K device-scope
// atomicAdd-with-return into a 3.1 KB cursor array (49 lines, few L2
// channels) -> ~3.1K serialized cross-XCD RMWs per line ~= the whole 57 us.
// Fix: one cursor per 64 B line (cnt[16 + cb*16], 50 KB) -> 196 atomics
// per line, spread over 782 lines / all channels. Everything else is
// round-18 verbatim (records {j|bf16(v)}, alpha computed in gather).
#define CAPN 48
#define OVF_IDX 0                     // cnt[0] = global overflow cursor
#define OMAX 4096
#define LOVF 64                       // block-local bucket-spill capacity

#define CPAD 16                       // ints per cursor slot (64 B line)

#define RB_BITS 7
#define RBUK (1 << RB_BITS)                   // 128 buckets per region
#define NBUCK (2 * N_NODES)                   // 100000 buckets
#define NREG ((NBUCK + RBUK - 1) >> RB_BITS)  // 782 regions (last partial)
#define RCAP 2560                             // lambda=2048, +11sigma
#define EPB 8192                              // edges per scatter block
#define NP1 ((2 * N_EDGES + EPB - 1) / EPB)   // 196 scatter blocks
#define NPREB 784                             // pre blocks (64 rows @512 thr)
#define NK1 (NP1 + NPREB)                     // 980; b%5==0 -> scatter role

#define ZERON (CPAD + NREG * CPAD)    // ovf line + padded region cursors

typedef __attribute__((ext_vector_type(8))) unsigned short u16x8;

__device__ __forceinline__ unsigned short f2bf(float f) {
    unsigned u = __float_as_uint(f);
    return (unsigned short)((u + 0x7FFFu + ((u >> 16) & 1u)) >> 16);
}
__device__ __forceinline__ float bf2f(unsigned short b) {
    return __uint_as_float(((unsigned)b) << 16);
}

// ---------------------------------------------------------------------------
// Kernel 1 (fused): GEMM precompute + s-dots + pass-1 region scatter.
// Scatter role (b%5==0): 8192 edges/block, single pass, records
//   {j<<16 | bf16(v)} held in regs/AGPRs across the barriers; only
//   coalesced edge reads + LDS hist + line-padded cursor reservation.
// Pre role: 8 waves x 8 rows; f32 GEMM accumulators -> xm_l/xm_u/xlin
//   stores + 4 per-row shuffle-reduce dots with a_l/a_u -> ssl/stl/ssu/stu.
// ---------------------------------------------------------------------------
__global__ __launch_bounds__(512) void gemm_scatter_kernel(
    const float* __restrict__ x,
    const float* __restrict__ w_l, const float* __restrict__ a_l,
    const float* __restrict__ w_u, const float* __restrict__ a_u,
    const float* __restrict__ w_lin,
    const int* __restrict__ lidx, const float* __restrict__ lval,
    const int* __restrict__ uidx, const float* __restrict__ uval,
    unsigned short* __restrict__ xm_l, unsigned short* __restrict__ xm_u,
    float* __restrict__ xlin,
    float* __restrict__ ssl, float* __restrict__ stl,
    float* __restrict__ ssu, float* __restrict__ stu,
    int* __restrict__ cnt, uint2* __restrict__ rbuf, int2* __restrict__ ovf)
{
    const int b = blockIdx.x, t = threadIdx.x;
    __shared__ int hist[NREG];        // 3.1 KB; count -> base/cursor in place

    if (b % 5 == 0) {
        // ---- pass-1 scatter role (single-pass) ----
        const int p = b / 5;
        int* __restrict__ rcur = cnt + CPAD;   // rcur[cb*CPAD], one per line

        for (int s0 = t; s0 < NREG; s0 += 512) hist[s0] = 0;
        __syncthreads();

        unsigned lo[16];
        int bk[16];
        const int gbase = p * EPB + t;
#pragma unroll
        for (int k = 0; k < 16; ++k) {
            const int g = gbase + k * 512;
            bk[k] = -1;
            if (g < 2 * N_EDGES) {
                int i, j;
                float v;
                if (g < N_EDGES) {
                    i = lidx[g]; j = lidx[N_EDGES + g]; v = lval[g];
                    bk[k] = 2 * i;
                } else {
                    const int e = g - N_EDGES;
                    i = uidx[e]; j = uidx[N_EDGES + e]; v = uval[e];
                    bk[k] = 2 * i + 1;
                }
                lo[k] = ((unsigned)j << 16) | (unsigned)f2bf(v);
                atomicAdd(&hist[bk[k] >> RB_BITS], 1);
            }
        }
        __syncthreads();

        for (int cb = t; cb < NREG; cb += 512) {
            const int c = hist[cb];
            // count -> global base (line-padded cursor: 196 atomics/line max)
            hist[cb] = c ? atomicAdd(&rcur[cb * CPAD], c) : 0;
        }
        __syncthreads();

#pragma unroll
        for (int k = 0; k < 16; ++k) {
            if (bk[k] >= 0) {
                const int cb = bk[k] >> RB_BITS;
                const int slot = atomicAdd(&hist[cb], 1); // global slot in region
                if (slot < RCAP) {
                    rbuf[(size_t)cb * RCAP + slot] = make_uint2(lo[k], (unsigned)bk[k]);
                } else {
                    const int oi = atomicAdd(&cnt[OVF_IDX], 1);
                    if (oi < OMAX) ovf[oi] = make_int2(bk[k], (int)lo[k]);
                }
            }
        }
        return;
    }

    // ---- pre role: rows pid*64 .. +63 (8 waves x 8 rows) ----
    const int pid = b - b / 5 - 1;
    const int lane = t & 63;
    const int wvu = __builtin_amdgcn_readfirstlane(t >> 6);
    const int row0 = pid * 64 + wvu * 8;
    if (row0 >= N_NODES) return;

    const float* xr[8];
#pragma unroll
    for (int r = 0; r < 8; ++r) {
        int rr = row0 + r;
        if (rr >= N_NODES) rr = N_NODES - 1;
        xr[r] = x + (size_t)rr * C;
    }

    float acc_l[8] = {0,0,0,0,0,0,0,0};
    float acc_u[8] = {0,0,0,0,0,0,0,0};
    float acc_n[8] = {0,0,0,0,0,0,0,0};

#pragma unroll 1
    for (int kc = 0; kc < C; kc += 4) {
#pragma unroll
        for (int kk = 0; kk < 4; ++kk) {
            const int k = kc + kk;
            const float wl = w_l[k * C + lane];
            const float wu = w_u[k * C + lane];
            const float wn = w_lin[k * C + lane];
#pragma unroll
            for (int r = 0; r < 8; ++r) {
                const float xk = xr[r][k];      // wave-uniform -> scalar load
                acc_l[r] = fmaf(xk, wl, acc_l[r]);
                acc_u[r] = fmaf(xk, wu, acc_u[r]);
                acc_n[r] = fmaf(xk, wn, acc_n[r]);
            }
        }
    }

    // a-vectors for the fused s-dots (coalesced, L2-hot)
    const float als = a_l[lane], alt = a_l[C + lane];
    const float aus = a_u[lane], aut = a_u[C + lane];

#pragma unroll
    for (int r = 0; r < 8; ++r) {
        const int row = row0 + r;
        if (row < N_NODES) {
            xm_l[row * C + lane] = f2bf(acc_l[r]);
            xm_u[row * C + lane] = f2bf(acc_u[r]);
            xlin[row * C + lane] = acc_n[r] * EPS_F;

            // s-dots: ssl = xm_l_row . a_l[:64], stl = xm_l_row . a_l[64:],
            //         ssu/stu likewise with a_u (f32 accumulators)
            float psl = acc_l[r] * als, ptl = acc_l[r] * alt;
            float psu = acc_u[r] * aus, ptu = acc_u[r] * aut;
#pragma unroll
            for (int o = 32; o >= 1; o >>= 1) {
                psl += __shfl_xor(psl, o);
                ptl += __shfl_xor(ptl, o);
                psu += __shfl_xor(psu, o);
                ptu += __shfl_xor(ptu, o);
            }
            if (lane == 0) {
                ssl[row] = psl; stl[row] = ptl;
                ssu[row] = psu; stu[row] = ptu;
            }
        }
    }
}

// ---------------------------------------------------------------------------
// Kernel 2: gather v10 — one block per REGION (64 nodes x 2 convs).
// Phase 1: coalesced read of the region's dense chunk, LDS-atomic sort into
//          128 LDS lists; bucket spills -> local LDS list.
// Phase 2: per node, interleaved conv-0/conv-1 walk; records carry
//          {j | bf16(v)} so alpha = elu(ssl[j] + stl[node]) * v is computed
//          here (ssl/ssu 200 KB L2-resident; stl/stu wave-uniform per node;
//          elu chain overlaps the independent xm row loads).
// ---------------------------------------------------------------------------
__global__ __launch_bounds__(512) void gather_kernel(
    const float* __restrict__ xlin,
    const int* __restrict__ cnt, const uint2* __restrict__ rbuf,
    const int2* __restrict__ ovf,
    const unsigned short* __restrict__ xm_l, const unsigned short* __restrict__ xm_u,
    const float* __restrict__ ssl, const float* __restrict__ stl,
    const float* __restrict__ ssu, const float* __restrict__ stu,
    float* __restrict__ out)
{
    const int cb = blockIdx.x;
    const int t = threadIdx.x;
    const int wv = t >> 6, lane = t & 63;
    const int sub8 = lane >> 3;
    const int cg = lane & 7;

    __shared__ unsigned lists[RBUK * CAPN];  // 24.6 KB
    __shared__ int cur[RBUK];
    __shared__ int lovf_bk[LOVF];
    __shared__ unsigned lovf_rc[LOVF];
    __shared__ int lc;

    for (int s0 = t; s0 < RBUK; s0 += 512) cur[s0] = 0;
    if (t == 0) lc = 0;
    __syncthreads();

    // ---- phase 1: distribute region chunk into LDS lists ----
    const int n = min(cnt[CPAD + cb * CPAD], RCAP);
    const uint2* __restrict__ rb = rbuf + (size_t)cb * RCAP;
    for (int r = t; r < n; r += 512) {
        const uint2 e = rb[r];
        const int local = (int)e.y & (RBUK - 1);
        const int rank = atomicAdd(&cur[local], 1);
        if (rank < CAPN) {
            lists[local * CAPN + rank] = e.x;
        } else {
            const int o = atomicAdd(&lc, 1);
            if (o < LOVF) { lovf_bk[o] = local; lovf_rc[o] = e.x; }
        }
    }
    __syncthreads();

    const int oc = min(cnt[OVF_IDX], OMAX);
    const int lc2 = min(lc, LOVF);

    // ---- phase 2: per-node interleaved walk out of LDS ----
#pragma unroll 1
    for (int p = 0; p < 8; ++p) {
        const int q = wv * 8 + p;
        const int node = cb * 64 + q;
        if (node >= N_NODES) break;
        const int lA = 2 * q, lB = 2 * q + 1;
        const int lenA = min(cur[lA], CAPN);
        const int lenB = min(cur[lB], CAPN);
        const unsigned* __restrict__ lstA = lists + lA * CAPN;
        const unsigned* __restrict__ lstB = lists + lB * CAPN;

        const float stlN = stl[node];
        const float stuN = stu[node];

        float acc[8] = {0.f,0.f,0.f,0.f,0.f,0.f,0.f,0.f};
        int kA = 0, kB = 0;
        while ((kA < lenA) | (kB < lenB)) {
            const int iA = kA + sub8, iB = kB + sub8;
            const bool aA = iA < lenA, aB = iB < lenB;
            const unsigned rwA = lstA[aA ? iA : kA];
            const unsigned rwB = lstB[aB ? iB : kB];
            const int jA = aA ? (int)(rwA >> 16) : 0;
            const int jB = aB ? (int)(rwB >> 16) : 0;
            const float vA = aA ? bf2f((unsigned short)(rwA & 0xFFFFu)) : 0.f;
            const float vB = aB ? bf2f((unsigned short)(rwB & 0xFFFFu)) : 0.f;
            // alpha = elu(s_src[j] + s_tgt[i]) * v   (vA=0 kills inactive lanes)
            const float sA = ssl[jA] + stlN;
            const float sB = ssu[jB] + stuN;
            const float eA = (sA > 0.f) ? sA : expm1f(sA);
            const float eB = (sB > 0.f) ? sB : expm1f(sB);
            const float wA = eA * vA;
            const float wB = eB * vB;
            const u16x8 rowA = *(const u16x8*)(xm_l + jA * C + cg * 8);
            const u16x8 rowB = *(const u16x8*)(xm_u + jB * C + cg * 8);
#pragma unroll
            for (int c = 0; c < 8; ++c)
                acc[c] = fmaf(wA, bf2f(rowA[c]), acc[c]);
#pragma unroll
            for (int c = 0; c < 8; ++c)
                acc[c] = fmaf(wB, bf2f(rowB[c]), acc[c]);
            kA += (kA < lenA) ? 8 : 0;
            kB += (kB < lenB) ? 8 : 0;
        }

        // global (region-spill) overflow tail — expected empty
        for (int u = 0; u < oc; ++u) {
            const int2 e = ovf[u];
            if (e.x == 2 * node || e.x == 2 * node + 1) {
                const unsigned rw = (unsigned)e.y;
                const int j = (int)(rw >> 16);
                const float v = bf2f((unsigned short)(rw & 0xFFFFu));
                const int cv = e.x & 1;
                const float s = (cv ? ssu[j] : ssl[j]) + (cv ? stuN : stlN);
                const float el = (s > 0.f) ? s : expm1f(s);
                const float w = (sub8 == 0) ? el * v : 0.f;
                const unsigned short* xm = cv ? xm_u : xm_l;
                const u16x8 row = *(const u16x8*)(xm + j * C + cg * 8);
#pragma unroll
                for (int c = 0; c < 8; ++c)
                    acc[c] = fmaf(w, bf2f(row[c]), acc[c]);
            }
        }

        // local (bucket-spill) overflow tail — expected empty
        for (int u = 0; u < lc2; ++u) {
            const int bkl = lovf_bk[u];
            if (bkl == lA || bkl == lB) {
                const unsigned rw = lovf_rc[u];
                const int j = (int)(rw >> 16);
                const float v = bf2f((unsigned short)(rw & 0xFFFFu));
                const int cv = bkl & 1;
                const float s = (cv ? ssu[j] : ssl[j]) + (cv ? stuN : stlN);
                const float el = (s > 0.f) ? s : expm1f(s);
                const float w = (sub8 == 0) ? el * v : 0.f;
                const unsigned short* xm = cv ? xm_u : xm_l;
                const u16x8 row = *(const u16x8*)(xm + j * C + cg * 8);
#pragma unroll
                for (int c = 0; c < 8; ++c)
                    acc[c] = fmaf(w, bf2f(row[c]), acc[c]);
            }
        }

        // reduce over the 8 record slots (lane bits 3..5)
#pragma unroll
        for (int o = 8; o <= 32; o <<= 1)
#pragma unroll
            for (int c = 0; c < 8; ++c)
                acc[c] += __shfl_xor(acc[c], o);

        if (lane < 8) {
            const float* __restrict__ xl = xlin + (size_t)node * C + lane * 8;
            const float4 xa = *(const float4*)(xl);
            const float4 xb = *(const float4*)(xl + 4);
            float4 oa, ob;
            oa.x = fmaxf(acc[0] + xa.x, 0.f);
            oa.y = fmaxf(acc[1] + xa.y, 0.f);
            oa.z = fmaxf(acc[2] + xa.z, 0.f);
            oa.w = fmaxf(acc[3] + xa.w, 0.f);
            ob.x = fmaxf(acc[4] + xb.x, 0.f);
            ob.y = fmaxf(acc[5] + xb.y, 0.f);
            ob.z = fmaxf(acc[6] + xb.z, 0.f);
            ob.w = fmaxf(acc[7] + xb.w, 0.f);
            float* __restrict__ op = out + (size_t)node * C + lane * 8;
            *(float4*)(op) = oa;
            *(float4*)(op + 4) = ob;
        }
    }
}

extern "C" void kernel_launch(void* const* d_in, const int* in_sizes, int n_in,
                              void* d_out, int out_size, void* d_ws, size_t ws_size,
                              hipStream_t stream)
{
    const float* x          = (const float*)d_in[0];
    const int*   lower_idx  = (const int*)d_in[1];
    const float* lower_vals = (const float*)d_in[2];
    const int*   upper_idx  = (const int*)d_in[3];
    const float* upper_vals = (const float*)d_in[4];
    const float* w_lower    = (const float*)d_in[5];
    const float* a_lower    = (const float*)d_in[6];
    const float* w_upper    = (const float*)d_in[7];
    const float* a_upper    = (const float*)d_in[8];
    const float* w_lin      = (const float*)d_in[9];

    float* out = (float*)d_out;
    char* ws = (char*)d_ws;

    // ---- workspace layout (~43 MB) ----
    const size_t NC_F = (size_t)N_NODES * C * sizeof(float);
    const size_t NC_H = (size_t)N_NODES * C * sizeof(unsigned short);
    unsigned short* xm_l = (unsigned short*)ws;  ws += NC_H;
    unsigned short* xm_u = (unsigned short*)ws;  ws += NC_H;
    float* xlin = (float*)ws;                 ws += NC_F;
    float* ssl  = (float*)ws;                 ws += N_NODES * sizeof(float);
    float* stl  = (float*)ws;                 ws += N_NODES * sizeof(float);
    float* ssu  = (float*)ws;                 ws += N_NODES * sizeof(float);
    float* stu  = (float*)ws;                 ws += N_NODES * sizeof(float);
    int2* ovf   = (int2*)ws;                  ws += OMAX * sizeof(int2);
    uint2* rbuf = (uint2*)ws;                 ws += (size_t)NREG * RCAP * sizeof(uint2); // 16.0 MB
    int* cnt    = (int*)ws;                   ws += (size_t)(ZERON + 64) * sizeof(int);  // 50 KB

    // K0: zero cursors (ovf line + padded region cursors) — 50 KB
    hipMemsetAsync(cnt, 0, ZERON * sizeof(int), stream);

    // K1: fused GEMM precompute + s-dots + pass-1 region scatter
    gemm_scatter_kernel<<<NK1, 512, 0, stream>>>(
        x, w_lower, a_lower, w_upper, a_upper, w_lin,
        lower_idx, lower_vals, upper_idx, upper_vals,
        xm_l, xm_u, xlin, ssl, stl, ssu, stu, cnt, rbuf, ovf);

    // K2: gather v10 (region-resident distribute + alpha + walk) + skip + relu
    gather_kernel<<<NREG, 512, 0, stream>>>(
        xlin, cnt, rbuf, ovf, xm_l, xm_u, ssl, stl, ssu, stu, out);
}

// Round 6
// 183.557 us; speedup vs baseline: 1.0022x; 1.0022x over previous
//
#include <hip/hip_runtime.h>
#include <hip/hip_bf16.h>
#include <math.h>

#define N_NODES 50000
#define N_EDGES 800000
#define C 64
#define EPS_F 1.000001f

// ---- round-20: double scatter parallelism; revert cursor padding ----
// Round-19 falsified pass-B line contention (padding: no dur change, +9 MB
// writeback). Surviving theory: the scatter role's ~55 us is per-block
// serialized work on a mostly-idle machine (196 blocks = 0.77/CU, 2
// waves/SIMD after the pre role retires at ~11 us; occupancy 35% confirms).
// Lever: EPB 8192 -> 4096 => 392 scatter blocks, 8 edges/thread. Pass-B
// atomics rise to 307K over 49 unpadded lines (6.3K/line, 2x the proven-
// harmless round-18 density) - deliberate 2x step, not 4x, to avoid
// creating a fresh atomic wall. Everything else is round-18 verbatim.
#define CAPN 48
#define OVF_IDX 0                     // cnt[0] = global overflow cursor
#define OMAX 4096
#define LOVF 64                       // block-local bucket-spill capacity

#define RB_BITS 7
#define RBUK (1 << RB_BITS)                   // 128 buckets per region
#define NBUCK (2 * N_NODES)                   // 100000 buckets
#define NREG ((NBUCK + RBUK - 1) >> RB_BITS)  // 782 regions (last partial)
#define RCAP 2560                             // lambda=2048, +11sigma
#define EPB 4096                              // edges per scatter block
#define NP1 392                               // scatter blocks (392*4096 >= 2E)
#define NPREB 784                             // pre blocks (64 rows @512 thr)
#define NK1 (3 * NP1)                         // 1176; b%3==0 -> scatter role

#define ZERON (1 + NREG)              // ovf cursor + region cursors

typedef __attribute__((ext_vector_type(8))) unsigned short u16x8;

__device__ __forceinline__ unsigned short f2bf(float f) {
    unsigned u = __float_as_uint(f);
    return (unsigned short)((u + 0x7FFFu + ((u >> 16) & 1u)) >> 16);
}
__device__ __forceinline__ float bf2f(unsigned short b) {
    return __uint_as_float(((unsigned)b) << 16);
}

// ---------------------------------------------------------------------------
// Kernel 1 (fused): GEMM precompute + s-dots + pass-1 region scatter.
// Scatter role (b%3==0): 4096 edges/block, single pass, records
//   {j<<16 | bf16(v)} held in regs/AGPRs across the barriers; only
//   coalesced edge reads + LDS hist + cursor reservation + chunk stores.
// Pre role: 8 waves x 8 rows; f32 GEMM accumulators -> xm_l/xm_u/xlin
//   stores + 4 per-row shuffle-reduce dots with a_l/a_u -> ssl/stl/ssu/stu.
// ---------------------------------------------------------------------------
__global__ __launch_bounds__(512) void gemm_scatter_kernel(
    const float* __restrict__ x,
    const float* __restrict__ w_l, const float* __restrict__ a_l,
    const float* __restrict__ w_u, const float* __restrict__ a_u,
    const float* __restrict__ w_lin,
    const int* __restrict__ lidx, const float* __restrict__ lval,
    const int* __restrict__ uidx, const float* __restrict__ uval,
    unsigned short* __restrict__ xm_l, unsigned short* __restrict__ xm_u,
    float* __restrict__ xlin,
    float* __restrict__ ssl, float* __restrict__ stl,
    float* __restrict__ ssu, float* __restrict__ stu,
    int* __restrict__ cnt, uint2* __restrict__ rbuf, int2* __restrict__ ovf)
{
    const int b = blockIdx.x, t = threadIdx.x;
    __shared__ int hist[NREG];        // 3.1 KB; count -> base/cursor in place

    if (b % 3 == 0) {
        // ---- pass-1 scatter role (single-pass) ----
        const int p = b / 3;
        int* __restrict__ rcur = cnt + 1;

        for (int s0 = t; s0 < NREG; s0 += 512) hist[s0] = 0;
        __syncthreads();

        unsigned lo[8];
        int bk[8];
        const int gbase = p * EPB + t;
#pragma unroll
        for (int k = 0; k < 8; ++k) {
            const int g = gbase + k * 512;
            bk[k] = -1;
            if (g < 2 * N_EDGES) {
                int i, j;
                float v;
                if (g < N_EDGES) {
                    i = lidx[g]; j = lidx[N_EDGES + g]; v = lval[g];
                    bk[k] = 2 * i;
                } else {
                    const int e = g - N_EDGES;
                    i = uidx[e]; j = uidx[N_EDGES + e]; v = uval[e];
                    bk[k] = 2 * i + 1;
                }
                lo[k] = ((unsigned)j << 16) | (unsigned)f2bf(v);
                atomicAdd(&hist[bk[k] >> RB_BITS], 1);
            }
        }
        __syncthreads();

        for (int cb = t; cb < NREG; cb += 512) {
            const int c = hist[cb];
            hist[cb] = c ? atomicAdd(&rcur[cb], c) : 0;   // count -> global base
        }
        __syncthreads();

#pragma unroll
        for (int k = 0; k < 8; ++k) {
            if (bk[k] >= 0) {
                const int cb = bk[k] >> RB_BITS;
                const int slot = atomicAdd(&hist[cb], 1); // global slot in region
                if (slot < RCAP) {
                    rbuf[(size_t)cb * RCAP + slot] = make_uint2(lo[k], (unsigned)bk[k]);
                } else {
                    const int oi = atomicAdd(&cnt[OVF_IDX], 1);
                    if (oi < OMAX) ovf[oi] = make_int2(bk[k], (int)lo[k]);
                }
            }
        }
        return;
    }

    // ---- pre role: rows pid*64 .. +63 (8 waves x 8 rows) ----
    const int pid = b - b / 3 - 1;
    const int lane = t & 63;
    const int wvu = __builtin_amdgcn_readfirstlane(t >> 6);
    const int row0 = pid * 64 + wvu * 8;
    if (row0 >= N_NODES) return;

    const float* xr[8];
#pragma unroll
    for (int r = 0; r < 8; ++r) {
        int rr = row0 + r;
        if (rr >= N_NODES) rr = N_NODES - 1;
        xr[r] = x + (size_t)rr * C;
    }

    float acc_l[8] = {0,0,0,0,0,0,0,0};
    float acc_u[8] = {0,0,0,0,0,0,0,0};
    float acc_n[8] = {0,0,0,0,0,0,0,0};

#pragma unroll 1
    for (int kc = 0; kc < C; kc += 4) {
#pragma unroll
        for (int kk = 0; kk < 4; ++kk) {
            const int k = kc + kk;
            const float wl = w_l[k * C + lane];
            const float wu = w_u[k * C + lane];
            const float wn = w_lin[k * C + lane];
#pragma unroll
            for (int r = 0; r < 8; ++r) {
                const float xk = xr[r][k];      // wave-uniform -> scalar load
                acc_l[r] = fmaf(xk, wl, acc_l[r]);
                acc_u[r] = fmaf(xk, wu, acc_u[r]);
                acc_n[r] = fmaf(xk, wn, acc_n[r]);
            }
        }
    }

    // a-vectors for the fused s-dots (coalesced, L2-hot)
    const float als = a_l[lane], alt = a_l[C + lane];
    const float aus = a_u[lane], aut = a_u[C + lane];

#pragma unroll
    for (int r = 0; r < 8; ++r) {
        const int row = row0 + r;
        if (row < N_NODES) {
            xm_l[row * C + lane] = f2bf(acc_l[r]);
            xm_u[row * C + lane] = f2bf(acc_u[r]);
            xlin[row * C + lane] = acc_n[r] * EPS_F;

            // s-dots: ssl = xm_l_row . a_l[:64], stl = xm_l_row . a_l[64:],
            //         ssu/stu likewise with a_u (f32 accumulators)
            float psl = acc_l[r] * als, ptl = acc_l[r] * alt;
            float psu = acc_u[r] * aus, ptu = acc_u[r] * aut;
#pragma unroll
            for (int o = 32; o >= 1; o >>= 1) {
                psl += __shfl_xor(psl, o);
                ptl += __shfl_xor(ptl, o);
                psu += __shfl_xor(psu, o);
                ptu += __shfl_xor(ptu, o);
            }
            if (lane == 0) {
                ssl[row] = psl; stl[row] = ptl;
                ssu[row] = psu; stu[row] = ptu;
            }
        }
    }
}

// ---------------------------------------------------------------------------
// Kernel 2: gather v10 — one block per REGION (64 nodes x 2 convs).
// Phase 1: coalesced read of the region's dense chunk, LDS-atomic sort into
//          128 LDS lists; bucket spills -> local LDS list.
// Phase 2: per node, interleaved conv-0/conv-1 walk; records carry
//          {j | bf16(v)} so alpha = elu(ssl[j] + stl[node]) * v is computed
//          here (ssl/ssu 200 KB L2-resident; stl/stu wave-uniform per node;
//          elu chain overlaps the independent xm row loads).
// ---------------------------------------------------------------------------
__global__ __launch_bounds__(512) void gather_kernel(
    const float* __restrict__ xlin,
    const int* __restrict__ cnt, const uint2* __restrict__ rbuf,
    const int2* __restrict__ ovf,
    const unsigned short* __restrict__ xm_l, const unsigned short* __restrict__ xm_u,
    const float* __restrict__ ssl, const float* __restrict__ stl,
    const float* __restrict__ ssu, const float* __restrict__ stu,
    float* __restrict__ out)
{
    const int cb = blockIdx.x;
    const int t = threadIdx.x;
    const int wv = t >> 6, lane = t & 63;
    const int sub8 = lane >> 3;
    const int cg = lane & 7;

    __shared__ unsigned lists[RBUK * CAPN];  // 24.6 KB
    __shared__ int cur[RBUK];
    __shared__ int lovf_bk[LOVF];
    __shared__ unsigned lovf_rc[LOVF];
    __shared__ int lc;

    for (int s0 = t; s0 < RBUK; s0 += 512) cur[s0] = 0;
    if (t == 0) lc = 0;
    __syncthreads();

    // ---- phase 1: distribute region chunk into LDS lists ----
    const int n = min(cnt[1 + cb], RCAP);
    const uint2* __restrict__ rb = rbuf + (size_t)cb * RCAP;
    for (int r = t; r < n; r += 512) {
        const uint2 e = rb[r];
        const int local = (int)e.y & (RBUK - 1);
        const int rank = atomicAdd(&cur[local], 1);
        if (rank < CAPN) {
            lists[local * CAPN + rank] = e.x;
        } else {
            const int o = atomicAdd(&lc, 1);
            if (o < LOVF) { lovf_bk[o] = local; lovf_rc[o] = e.x; }
        }
    }
    __syncthreads();

    const int oc = min(cnt[OVF_IDX], OMAX);
    const int lc2 = min(lc, LOVF);

    // ---- phase 2: per-node interleaved walk out of LDS ----
#pragma unroll 1
    for (int p = 0; p < 8; ++p) {
        const int q = wv * 8 + p;
        const int node = cb * 64 + q;
        if (node >= N_NODES) break;
        const int lA = 2 * q, lB = 2 * q + 1;
        const int lenA = min(cur[lA], CAPN);
        const int lenB = min(cur[lB], CAPN);
        const unsigned* __restrict__ lstA = lists + lA * CAPN;
        const unsigned* __restrict__ lstB = lists + lB * CAPN;

        const float stlN = stl[node];
        const float stuN = stu[node];

        float acc[8] = {0.f,0.f,0.f,0.f,0.f,0.f,0.f,0.f};
        int kA = 0, kB = 0;
        while ((kA < lenA) | (kB < lenB)) {
            const int iA = kA + sub8, iB = kB + sub8;
            const bool aA = iA < lenA, aB = iB < lenB;
            const unsigned rwA = lstA[aA ? iA : kA];
            const unsigned rwB = lstB[aB ? iB : kB];
            const int jA = aA ? (int)(rwA >> 16) : 0;
            const int jB = aB ? (int)(rwB >> 16) : 0;
            const float vA = aA ? bf2f((unsigned short)(rwA & 0xFFFFu)) : 0.f;
            const float vB = aB ? bf2f((unsigned short)(rwB & 0xFFFFu)) : 0.f;
            // alpha = elu(s_src[j] + s_tgt[i]) * v   (vA=0 kills inactive lanes)
            const float sA = ssl[jA] + stlN;
            const float sB = ssu[jB] + stuN;
            const float eA = (sA > 0.f) ? sA : expm1f(sA);
            const float eB = (sB > 0.f) ? sB : expm1f(sB);
            const float wA = eA * vA;
            const float wB = eB * vB;
            const u16x8 rowA = *(const u16x8*)(xm_l + jA * C + cg * 8);
            const u16x8 rowB = *(const u16x8*)(xm_u + jB * C + cg * 8);
#pragma unroll
            for (int c = 0; c < 8; ++c)
                acc[c] = fmaf(wA, bf2f(rowA[c]), acc[c]);
#pragma unroll
            for (int c = 0; c < 8; ++c)
                acc[c] = fmaf(wB, bf2f(rowB[c]), acc[c]);
            kA += (kA < lenA) ? 8 : 0;
            kB += (kB < lenB) ? 8 : 0;
        }

        // global (region-spill) overflow tail — expected empty
        for (int u = 0; u < oc; ++u) {
            const int2 e = ovf[u];
            if (e.x == 2 * node || e.x == 2 * node + 1) {
                const unsigned rw = (unsigned)e.y;
                const int j = (int)(rw >> 16);
                const float v = bf2f((unsigned short)(rw & 0xFFFFu));
                const int cv = e.x & 1;
                const float s = (cv ? ssu[j] : ssl[j]) + (cv ? stuN : stlN);
                const float el = (s > 0.f) ? s : expm1f(s);
                const float w = (sub8 == 0) ? el * v : 0.f;
                const unsigned short* xm = cv ? xm_u : xm_l;
                const u16x8 row = *(const u16x8*)(xm + j * C + cg * 8);
#pragma unroll
                for (int c = 0; c < 8; ++c)
                    acc[c] = fmaf(w, bf2f(row[c]), acc[c]);
            }
        }

        // local (bucket-spill) overflow tail — expected empty
        for (int u = 0; u < lc2; ++u) {
            const int bkl = lovf_bk[u];
            if (bkl == lA || bkl == lB) {
                const unsigned rw = lovf_rc[u];
                const int j = (int)(rw >> 16);
                const float v = bf2f((unsigned short)(rw & 0xFFFFu));
                const int cv = bkl & 1;
                const float s = (cv ? ssu[j] : ssl[j]) + (cv ? stuN : stlN);
                const float el = (s > 0.f) ? s : expm1f(s);
                const float w = (sub8 == 0) ? el * v : 0.f;
                const unsigned short* xm = cv ? xm_u : xm_l;
                const u16x8 row = *(const u16x8*)(xm + j * C + cg * 8);
#pragma unroll
                for (int c = 0; c < 8; ++c)
                    acc[c] = fmaf(w, bf2f(row[c]), acc[c]);
            }
        }

        // reduce over the 8 record slots (lane bits 3..5)
#pragma unroll
        for (int o = 8; o <= 32; o <<= 1)
#pragma unroll
            for (int c = 0; c < 8; ++c)
                acc[c] += __shfl_xor(acc[c], o);

        if (lane < 8) {
            const float* __restrict__ xl = xlin + (size_t)node * C + lane * 8;
            const float4 xa = *(const float4*)(xl);
            const float4 xb = *(const float4*)(xl + 4);
            float4 oa, ob;
            oa.x = fmaxf(acc[0] + xa.x, 0.f);
            oa.y = fmaxf(acc[1] + xa.y, 0.f);
            oa.z = fmaxf(acc[2] + xa.z, 0.f);
            oa.w = fmaxf(acc[3] + xa.w, 0.f);
            ob.x = fmaxf(acc[4] + xb.x, 0.f);
            ob.y = fmaxf(acc[5] + xb.y, 0.f);
            ob.z = fmaxf(acc[6] + xb.z, 0.f);
            ob.w = fmaxf(acc[7] + xb.w, 0.f);
            float* __restrict__ op = out + (size_t)node * C + lane * 8;
            *(float4*)(op) = oa;
            *(float4*)(op + 4) = ob;
        }
    }
}

extern "C" void kernel_launch(void* const* d_in, const int* in_sizes, int n_in,
                              void* d_out, int out_size, void* d_ws, size_t ws_size,
                              hipStream_t stream)
{
    const float* x          = (const float*)d_in[0];
    const int*   lower_idx  = (const int*)d_in[1];
    const float* lower_vals = (const float*)d_in[2];
    const int*   upper_idx  = (const int*)d_in[3];
    const float* upper_vals = (const float*)d_in[4];
    const float* w_lower    = (const float*)d_in[5];
    const float* a_lower    = (const float*)d_in[6];
    const float* w_upper    = (const float*)d_in[7];
    const float* a_upper    = (const float*)d_in[8];
    const float* w_lin      = (const float*)d_in[9];

    float* out = (float*)d_out;
    char* ws = (char*)d_ws;

    // ---- workspace layout (~43 MB) ----
    const size_t NC_F = (size_t)N_NODES * C * sizeof(float);
    const size_t NC_H = (size_t)N_NODES * C * sizeof(unsigned short);
    unsigned short* xm_l = (unsigned short*)ws;  ws += NC_H;
    unsigned short* xm_u = (unsigned short*)ws;  ws += NC_H;
    float* xlin = (float*)ws;                 ws += NC_F;
    float* ssl  = (float*)ws;                 ws += N_NODES * sizeof(float);
    float* stl  = (float*)ws;                 ws += N_NODES * sizeof(float);
    float* ssu  = (float*)ws;                 ws += N_NODES * sizeof(float);
    float* stu  = (float*)ws;                 ws += N_NODES * sizeof(float);
    int2* ovf   = (int2*)ws;                  ws += OMAX * sizeof(int2);
    uint2* rbuf = (uint2*)ws;                 ws += (size_t)NREG * RCAP * sizeof(uint2); // 16.0 MB
    int* cnt    = (int*)ws;                   ws += (size_t)(ZERON + 64) * sizeof(int);

    // K0: zero cursors (ovf + region) — 3.1 KB
    hipMemsetAsync(cnt, 0, ZERON * sizeof(int), stream);

    // K1: fused GEMM precompute + s-dots + pass-1 region scatter
    gemm_scatter_kernel<<<NK1, 512, 0, stream>>>(
        x, w_lower, a_lower, w_upper, a_upper, w_lin,
        lower_idx, lower_vals, upper_idx, upper_vals,
        xm_l, xm_u, xlin, ssl, stl, ssu, stu, cnt, rbuf, ovf);

    // K2: gather v10 (region-resident distribute + alpha + walk) + skip + relu
    gather_kernel<<<NREG, 512, 0, stream>>>(
        xlin, cnt, rbuf, ovf, xm_l, xm_u, ssl, stl, ssu, stu, out);
}